// Round 1
// baseline (102.331 us; speedup 1.0000x reference)
//
#include <hip/hip_runtime.h>

#define NN 4194304
#define NB 16384

// Segmented wave-level reduction + one atomic pair per run.
// batch is sorted, so runs are contiguous within a wave.
__device__ __forceinline__ void seg_atomic_add2(int b, float vx, float vy,
                                                float* __restrict__ out) {
  const int lane = threadIdx.x & 63;
  int bprev = __shfl_up(b, 1);
  bool head = (lane == 0) || (b != bprev);
  unsigned long long hb = __ballot(head);
  // run_start = highest set head bit at or below my lane
  unsigned long long mask_le = hb << (63 - lane);
  int run_start = lane - __clzll(mask_le);
  float sx = vx, sy = vy;
#pragma unroll
  for (int off = 1; off < 64; off <<= 1) {
    float ox = __shfl_up(sx, off);
    float oy = __shfl_up(sy, off);
    if (lane - off >= run_start) { sx += ox; sy += oy; }
  }
  int bnext = __shfl_down(b, 1);
  bool tail = (lane == 63) || (b != bnext);
  if (tail) {
    atomicAdd(&out[2 * b], sx);
    atomicAdd(&out[2 * b + 1], sy);
  }
}

__global__ __launch_bounds__(256) void centroid_kernel(
    const float2* __restrict__ pos, const int* __restrict__ batch,
    float* __restrict__ csum) {
  int i = blockIdx.x * 256 + threadIdx.x;
  float2 p = pos[i];
  int b = batch[i];
  seg_atomic_add2(b, p.x, p.y, csum);
}

// Per-graph: unit vector of (centroid - poi_pos)
__global__ __launch_bounds__(256) void graphvec_kernel(
    const float* __restrict__ csum, const float2* __restrict__ poi_pos,
    float* __restrict__ udc) {
  int i = blockIdx.x * 256 + threadIdx.x;
  float2 pp = poi_pos[i];
  float dcx = csum[2 * i] - pp.x;
  float dcy = csum[2 * i + 1] - pp.y;
  float inv = rsqrtf(dcx * dcx + dcy * dcy);
  udc[2 * i] = dcx * inv;
  udc[2 * i + 1] = dcy * inv;
}

__global__ __launch_bounds__(256) void main_kernel(
    const float* __restrict__ t, const float2* __restrict__ pos,
    const float* __restrict__ poi_t, const float2* __restrict__ poi_pos,
    const int* __restrict__ batch, const float2* __restrict__ udc,
    const float* __restrict__ W1, const float* __restrict__ B1,
    const float* __restrict__ W2, const float* __restrict__ B2,
    const float* __restrict__ W3, const float* __restrict__ B3,
    const float* __restrict__ W4, const float* __restrict__ B4,
    const float* __restrict__ W5, const float* __restrict__ B5,
    float* __restrict__ out) {
  int i = blockIdx.x * 256 + threadIdx.x;
  int b = batch[i];
  float2 p = pos[i];
  float tv = t[i];
  float2 pp = poi_pos[b];
  float2 u = udc[b];
  float f0 = tv - poi_t[b];                      // diff_t
  float dpx = p.x - pp.x, dpy = p.y - pp.y;
  float f1 = dpx * dpx + dpy * dpy;              // r2
  float inv_r = rsqrtf(f1);
  float f2 = (dpx * u.x + dpy * u.y) * inv_r;    // cosine

  // MLP 3 -> 10 -> 20 -> 10 -> 5 -> 1, weights are wave-uniform (s_load)
  float h1[10];
#pragma unroll
  for (int j = 0; j < 10; ++j) {
    float a = B1[j];
    a += W1[j * 3 + 0] * f0;
    a += W1[j * 3 + 1] * f1;
    a += W1[j * 3 + 2] * f2;
    h1[j] = fmaxf(a, 0.0f);
  }
  float h2[20];
#pragma unroll
  for (int j = 0; j < 20; ++j) {
    float a = B2[j];
#pragma unroll
    for (int k = 0; k < 10; ++k) a += W2[j * 10 + k] * h1[k];
    h2[j] = fmaxf(a, 0.0f);
  }
  float h3[10];
#pragma unroll
  for (int j = 0; j < 10; ++j) {
    float a = B3[j];
#pragma unroll
    for (int k = 0; k < 20; ++k) a += W3[j * 20 + k] * h2[k];
    h3[j] = fmaxf(a, 0.0f);
  }
  float h4[5];
#pragma unroll
  for (int j = 0; j < 5; ++j) {
    float a = B4[j];
#pragma unroll
    for (int k = 0; k < 10; ++k) a += W4[j * 10 + k] * h3[k];
    h4[j] = fmaxf(a, 0.0f);
  }
  float w = B5[0];
#pragma unroll
  for (int k = 0; k < 5; ++k) w += W5[k] * h4[k];

  // F.normalize(diff_pos): norm clamped at 1e-12
  float nrm = fmaxf(sqrtf(f1), 1e-12f);
  float invn = 1.0f / nrm;
  seg_atomic_add2(b, w * dpx * invn, w * dpy * invn, out);
}

extern "C" void kernel_launch(void* const* d_in, const int* in_sizes, int n_in,
                              void* d_out, int out_size, void* d_ws,
                              size_t ws_size, hipStream_t stream) {
  const float* t = (const float*)d_in[0];
  const float2* pos = (const float2*)d_in[1];
  const float* poi_t = (const float*)d_in[2];
  const float2* poi_pos = (const float2*)d_in[3];
  const int* batch = (const int*)d_in[4];
  const float* W1 = (const float*)d_in[5];
  const float* B1 = (const float*)d_in[6];
  const float* W2 = (const float*)d_in[7];
  const float* B2 = (const float*)d_in[8];
  const float* W3 = (const float*)d_in[9];
  const float* B3 = (const float*)d_in[10];
  const float* W4 = (const float*)d_in[11];
  const float* B4 = (const float*)d_in[12];
  const float* W5 = (const float*)d_in[13];
  const float* B5 = (const float*)d_in[14];
  float* out = (float*)d_out;

  float* csum = (float*)d_ws;               // [NB*2]
  float* udc = csum + 2 * NB;               // [NB*2]

  hipMemsetAsync(csum, 0, 2 * NB * sizeof(float), stream);
  hipMemsetAsync(d_out, 0, 2 * NB * sizeof(float), stream);

  centroid_kernel<<<NN / 256, 256, 0, stream>>>(pos, batch, csum);
  graphvec_kernel<<<NB / 256, 256, 0, stream>>>(csum, poi_pos, (float*)udc);
  main_kernel<<<NN / 256, 256, 0, stream>>>(
      t, pos, poi_t, poi_pos, batch, (const float2*)udc, W1, B1, W2, B2, W3,
      B3, W4, B4, W5, B5, out);
}

// Round 3
// 87.812 us; speedup vs baseline: 1.1653x; 1.1653x over previous
//
#include <hip/hip_runtime.h>

#define NN 4194304
#define NB 16384

typedef _Float16 half2v __attribute__((ext_vector_type(2)));

__device__ __forceinline__ half2v pk(float lo, float hi) {
  return __builtin_bit_cast(half2v, __builtin_amdgcn_cvt_pkrtz(lo, hi));
}

__device__ __forceinline__ float fdot2(half2v a, half2v b, float c) {
#if __has_builtin(__builtin_amdgcn_fdot2)
  return __builtin_amdgcn_fdot2(a, b, c, false);
#else
  float r;
  asm("v_dot2_f32_f16 %0, %1, %2, %3" : "=v"(r) : "v"(a), "v"(b), "v"(c));
  return r;
#endif
}

// Segmented wave-level reduction + one atomic pair per run (batch sorted).
__device__ __forceinline__ void seg_atomic_add2(int b, float vx, float vy,
                                                float* __restrict__ out) {
  const int lane = threadIdx.x & 63;
  int bprev = __shfl_up(b, 1);
  bool head = (lane == 0) || (b != bprev);
  unsigned long long hb = __ballot(head);
  unsigned long long mask_le = hb << (63 - lane);
  int run_start = lane - __clzll(mask_le);
  float sx = vx, sy = vy;
#pragma unroll
  for (int off = 1; off < 64; off <<= 1) {
    float ox = __shfl_up(sx, off);
    float oy = __shfl_up(sy, off);
    if (lane - off >= run_start) { sx += ox; sy += oy; }
  }
  int bnext = __shfl_down(b, 1);
  bool tail = (lane == 63) || (b != bnext);
  if (tail) {
    atomicAdd(&out[2 * b], sx);
    atomicAdd(&out[2 * b + 1], sy);
  }
}

__global__ __launch_bounds__(256) void centroid_kernel(
    const float2* __restrict__ pos, const int* __restrict__ batch,
    float* __restrict__ csum) {
  int i = blockIdx.x * 256 + threadIdx.x;
  float2 p = pos[i];
  int b = batch[i];
  seg_atomic_add2(b, p.x, p.y, csum);
}

__global__ __launch_bounds__(256) void graphvec_kernel(
    const float* __restrict__ csum, const float2* __restrict__ poi_pos,
    float* __restrict__ udc) {
  int i = blockIdx.x * 256 + threadIdx.x;
  float2 pp = poi_pos[i];
  float dcx = csum[2 * i] - pp.x;
  float dcy = csum[2 * i + 1] - pp.y;
  float inv = rsqrtf(dcx * dcx + dcy * dcy);
  udc[2 * i] = dcx * inv;
  udc[2 * i + 1] = dcy * inv;
}

// Pack MLP weights into f16 pairs (K-dim pairs, K padded to even).
// Layout (uint index): L1 @0 (10 out x 2), L2 @20 (20 x 5), L3 @120 (10 x 10),
// L4 @220 (5 x 5), L5 @245 (1 x 3). Total 248.
__global__ void prepack_kernel(const float* __restrict__ W1,
                               const float* __restrict__ W2,
                               const float* __restrict__ W3,
                               const float* __restrict__ W4,
                               const float* __restrict__ W5,
                               unsigned* __restrict__ Wp) {
  int p = blockIdx.x * blockDim.x + threadIdx.x;
  if (p >= 248) return;
  float a = 0.f, b = 0.f;
  if (p < 20) {
    int j = p >> 1, k = (p & 1) * 2;
    a = W1[j * 3 + k];
    b = (k + 1 < 3) ? W1[j * 3 + k + 1] : 0.f;
  } else if (p < 120) {
    int q = p - 20, j = q / 5, k = (q % 5) * 2;
    a = W2[j * 10 + k];
    b = W2[j * 10 + k + 1];
  } else if (p < 220) {
    int q = p - 120, j = q / 10, k = (q % 10) * 2;
    a = W3[j * 20 + k];
    b = W3[j * 20 + k + 1];
  } else if (p < 245) {
    int q = p - 220, j = q / 5, k = (q % 5) * 2;
    a = W4[j * 10 + k];
    b = W4[j * 10 + k + 1];
  } else {
    int k = (p - 245) * 2;
    a = W5[k];
    b = (k + 1 < 5) ? W5[k + 1] : 0.f;
  }
  Wp[p] = __builtin_bit_cast(unsigned, pk(a, b));
}

#define WPK(i) __builtin_bit_cast(half2v, Wp[i])

__global__ __launch_bounds__(256) void main_kernel(
    const float* __restrict__ t, const float2* __restrict__ pos,
    const float* __restrict__ poi_t, const float2* __restrict__ poi_pos,
    const int* __restrict__ batch, const float2* __restrict__ udc,
    const unsigned* __restrict__ Wp,
    const float* __restrict__ B1, const float* __restrict__ B2,
    const float* __restrict__ B3, const float* __restrict__ B4,
    const float* __restrict__ B5,
    float* __restrict__ out) {
  int i = blockIdx.x * 256 + threadIdx.x;
  int b = batch[i];
  float2 p = pos[i];
  float tv = t[i];
  float2 pp = poi_pos[b];
  float2 u = udc[b];
  float f0 = tv - poi_t[b];
  float dpx = p.x - pp.x, dpy = p.y - pp.y;
  float f1 = dpx * dpx + dpy * dpy;
  float inv_r = rsqrtf(f1);
  float f2 = (dpx * u.x + dpy * u.y) * inv_r;

  // features packed to f16 pairs
  half2v x0 = pk(f0, f1);
  half2v x1 = pk(f2, 0.f);

  // L1: 3 -> 10
  float h1f[10];
#pragma unroll
  for (int j = 0; j < 10; ++j) {
    float a = B1[j];
    a = fdot2(x0, WPK(j * 2 + 0), a);
    a = fdot2(x1, WPK(j * 2 + 1), a);
    h1f[j] = fmaxf(a, 0.f);
  }
  half2v h1[5];
#pragma unroll
  for (int k = 0; k < 5; ++k) h1[k] = pk(h1f[2 * k], h1f[2 * k + 1]);

  // L2: 10 -> 20
  float h2f[20];
#pragma unroll
  for (int j = 0; j < 20; ++j) {
    float a = B2[j];
#pragma unroll
    for (int k = 0; k < 5; ++k) a = fdot2(h1[k], WPK(20 + j * 5 + k), a);
    h2f[j] = fmaxf(a, 0.f);
  }
  half2v h2[10];
#pragma unroll
  for (int k = 0; k < 10; ++k) h2[k] = pk(h2f[2 * k], h2f[2 * k + 1]);

  // L3: 20 -> 10
  float h3f[10];
#pragma unroll
  for (int j = 0; j < 10; ++j) {
    float a = B3[j];
#pragma unroll
    for (int k = 0; k < 10; ++k) a = fdot2(h2[k], WPK(120 + j * 10 + k), a);
    h3f[j] = fmaxf(a, 0.f);
  }
  half2v h3[5];
#pragma unroll
  for (int k = 0; k < 5; ++k) h3[k] = pk(h3f[2 * k], h3f[2 * k + 1]);

  // L4: 10 -> 5
  float h4f[5];
#pragma unroll
  for (int j = 0; j < 5; ++j) {
    float a = B4[j];
#pragma unroll
    for (int k = 0; k < 5; ++k) a = fdot2(h3[k], WPK(220 + j * 5 + k), a);
    h4f[j] = fmaxf(a, 0.f);
  }
  half2v h4[3];
  h4[0] = pk(h4f[0], h4f[1]);
  h4[1] = pk(h4f[2], h4f[3]);
  h4[2] = pk(h4f[4], 0.f);

  // L5: 5 -> 1
  float w = B5[0];
#pragma unroll
  for (int k = 0; k < 3; ++k) w = fdot2(h4[k], WPK(245 + k), w);

  float nrm = fmaxf(sqrtf(f1), 1e-12f);
  float invn = 1.0f / nrm;
  seg_atomic_add2(b, w * dpx * invn, w * dpy * invn, out);
}

extern "C" void kernel_launch(void* const* d_in, const int* in_sizes, int n_in,
                              void* d_out, int out_size, void* d_ws,
                              size_t ws_size, hipStream_t stream) {
  const float* t = (const float*)d_in[0];
  const float2* pos = (const float2*)d_in[1];
  const float* poi_t = (const float*)d_in[2];
  const float2* poi_pos = (const float2*)d_in[3];
  const int* batch = (const int*)d_in[4];
  const float* W1 = (const float*)d_in[5];
  const float* B1 = (const float*)d_in[6];
  const float* W2 = (const float*)d_in[7];
  const float* B2 = (const float*)d_in[8];
  const float* W3 = (const float*)d_in[9];
  const float* B3 = (const float*)d_in[10];
  const float* W4 = (const float*)d_in[11];
  const float* B4 = (const float*)d_in[12];
  const float* W5 = (const float*)d_in[13];
  const float* B5 = (const float*)d_in[14];
  float* out = (float*)d_out;

  float* csum = (float*)d_ws;                 // [NB*2]
  float* udc = csum + 2 * NB;                 // [NB*2]
  unsigned* Wp = (unsigned*)(udc + 2 * NB);   // [248]

  hipMemsetAsync(csum, 0, 2 * NB * sizeof(float), stream);
  hipMemsetAsync(d_out, 0, 2 * NB * sizeof(float), stream);

  prepack_kernel<<<1, 256, 0, stream>>>(W1, W2, W3, W4, W5, Wp);
  centroid_kernel<<<NN / 256, 256, 0, stream>>>(pos, batch, csum);
  graphvec_kernel<<<NB / 256, 256, 0, stream>>>(csum, poi_pos, udc);
  main_kernel<<<NN / 256, 256, 0, stream>>>(
      t, pos, poi_t, poi_pos, batch, (const float2*)udc, Wp, B1, B2, B3, B4,
      B5, out);
}